// Round 7
// baseline (538.698 us; speedup 1.0000x reference)
//
#include <hip/hip_runtime.h>
#include <hip/hip_bf16.h>

typedef __bf16 bf16;
typedef __attribute__((ext_vector_type(8))) __bf16 bf16x8;
typedef __attribute__((ext_vector_type(4))) __bf16 bf16x4;
typedef __attribute__((ext_vector_type(4))) float f32x4;
typedef __attribute__((ext_vector_type(16))) float f32x16;
typedef __attribute__((ext_vector_type(2))) int int2v;
typedef __attribute__((ext_vector_type(4))) int int4v;

#define HEADS 16
#define DHEAD 64
#define SEQ 2048
#define DIMM 1024
#define QKVN (3*DIMM)
#define SCALEQ 0.125f

__device__ __forceinline__ void gload_lds16(const bf16* g, bf16* l) {
  __builtin_amdgcn_global_load_lds(
      (const __attribute__((address_space(1))) void*)g,
      (__attribute__((address_space(3))) void*)l, 16, 0, 0);
}

__device__ __forceinline__ f32x16 mfma32(bf16x8 a, bf16x8 b, f32x16 c) {
  return __builtin_amdgcn_mfma_f32_32x32x16_bf16(a, b, c, 0, 0, 0);
}

__device__ __forceinline__ unsigned cvtpk(float a, float b) {
  unsigned r;
  asm("v_cvt_pk_bf16_f32 %0, %1, %2" : "=v"(r) : "v"(a), "v"(b));
  return r;
}

// ---------------- transpose + cast fp32 -> bf16 (out = in^T) ----------------
__global__ __launch_bounds__(256) void transpose_cast_k(const float* __restrict__ in,
                                                        bf16* __restrict__ out, int R, int C) {
  __shared__ bf16 tile[32][33];
  int bc = blockIdx.x, br = blockIdx.y;
  int t = threadIdx.x;
  int c = t & 31, r0 = t >> 5;
  for (int i = 0; i < 4; i++) {
    int r = r0 + i * 8;
    tile[r][c] = (bf16)in[(size_t)(br * 32 + r) * C + bc * 32 + c];
  }
  __syncthreads();
  for (int i = 0; i < 4; i++) {
    int r = r0 + i * 8;
    out[(size_t)(bc * 32 + r) * R + br * 32 + c] = tile[c][r];
  }
}

// ---------------- rope cos/sin table ----------------
__global__ void rope_table_k(const float* __restrict__ pos, float2* __restrict__ cs) {
  int i = blockIdx.x * 256 + threadIdx.x;  // 2048*64 = 131072
  float p = pos[i];
  cs[i] = make_float2(cosf(p), sinf(p));
}

// ---------------- layernorm fp32 -> bf16 ----------------
__global__ __launch_bounds__(256) void ln_k(const float* __restrict__ x, const float* __restrict__ w,
                                            const float* __restrict__ bsh, bf16* __restrict__ xn) {
  int row = blockIdx.x, t = threadIdx.x;
  const float4 v = reinterpret_cast<const float4*>(x + (size_t)row * DIMM)[t];
  float s1 = v.x + v.y + v.z + v.w;
  float s2 = v.x * v.x + v.y * v.y + v.z * v.z + v.w * v.w;
  for (int off = 1; off < 64; off <<= 1) {
    s1 += __shfl_xor(s1, off, 64);
    s2 += __shfl_xor(s2, off, 64);
  }
  __shared__ float red[8];
  int wv = t >> 6;
  if ((t & 63) == 0) { red[wv * 2] = s1; red[wv * 2 + 1] = s2; }
  __syncthreads();
  s1 = red[0] + red[2] + red[4] + red[6];
  s2 = red[1] + red[3] + red[5] + red[7];
  float mu = s1 * (1.0f / DIMM);
  float var = s2 * (1.0f / DIMM) - mu * mu;
  float rs = rsqrtf(var + 1e-5f);
  const float4 wv4 = reinterpret_cast<const float4*>(w)[t];
  const float4 bv4 = reinterpret_cast<const float4*>(bsh)[t];
  bf16x4 o;
  o[0] = (bf16)((v.x - mu) * rs * wv4.x + bv4.x);
  o[1] = (bf16)((v.y - mu) * rs * wv4.y + bv4.y);
  o[2] = (bf16)((v.z - mu) * rs * wv4.z + bv4.z);
  o[3] = (bf16)((v.w - mu) * rs * wv4.w + bv4.w);
  *reinterpret_cast<bf16x4*>(xn + (size_t)row * DIMM + t * 4) = o;
}

// ---------------- 256x256 pipelined bf16 GEMM: C[M,N] = A[M,K] * Bt[N,K]^T ----------------
// 512 threads (8 waves, 2Mx4N), BK=32, 4-slot LDS ring (128 KB), staging 3 K-tiles ahead
// with counted vmcnt; st_16x32 XOR swizzle (linear dest + inv-swz source + swz read).
__global__ __launch_bounds__(512, 2) void gemm256_k(const bf16* __restrict__ A, const bf16* __restrict__ Bt,
                                                    bf16* __restrict__ C, int Ndim, int K) {
  __shared__ bf16 lds[4][2][8192];   // [slot][A/B][256 rows x 32 cols]
  const int t = threadIdx.x, lane = t & 63, w = t >> 6;
  const int wr = w >> 2, wc = w & 3;
  const int lr = lane & 15, lg = lane >> 4;
  const int bn = blockIdx.x, bm = blockIdx.y;
  const bf16* Ab = A + (size_t)(bm * 256) * K;
  const bf16* Bb = Bt + (size_t)(bn * 256) * K;
  const int nt = K >> 5;   // K-tiles of 32 (requires nt >= 4)

  // stage chunks [i0,i1) of tile T into slot T&3 (4 chunks of 16B per thread per tile)
  auto STAGE = [&](int T, int i0, int i1) {
    int k0 = T << 5;
    for (int i = i0; i < i1; ++i) {
      int c = t + i * 512;               // 0..2047 chunks of 16B (A: 0..1023, B: 1024..2047)
      int Lt = c * 16;
      int isB = Lt >> 14;
      int Lh = Lt & 16383;               // byte within the 16 KB region
      int Ls = Lh ^ (((Lh >> 9) & 1) << 5);   // inverse-swizzled source byte
      int elem = Ls >> 1;
      int row = elem >> 5, col = elem & 31;
      const bf16* src = (isB ? Bb : Ab) + (size_t)row * K + k0 + col;
      gload_lds16(src, &lds[T & 3][isB][0] + (Lh >> 1));
    }
  };
  auto LDA = [&](int slot, int mi) -> bf16x8 {
    int row = wr * 128 + mi * 16 + lr;
    int L0 = row * 64 + lg * 16;
    int L = L0 ^ (((L0 >> 9) & 1) << 5);
    return *reinterpret_cast<const bf16x8*>(reinterpret_cast<const char*>(&lds[slot][0][0]) + L);
  };
  auto LDB = [&](int slot, int ni) -> bf16x8 {
    int row = wc * 64 + ni * 16 + lr;
    int L0 = row * 64 + lg * 16;
    int L = L0 ^ (((L0 >> 9) & 1) << 5);
    return *reinterpret_cast<const bf16x8*>(reinterpret_cast<const char*>(&lds[slot][1][0]) + L);
  };

  f32x4 acc[8][4] = {};
  STAGE(0, 0, 4); STAGE(1, 0, 4); STAGE(2, 0, 4);
  asm volatile("s_waitcnt vmcnt(8)" ::: "memory");   // tile 0 resident; tiles 1,2 in flight
  __builtin_amdgcn_s_barrier();
  __builtin_amdgcn_sched_barrier(0);

  for (int T = 0; T < nt; ++T) {
    int slot = T & 3;
    // ---- phase 0: B frags + A frags mi 0..3, stage first half of tile T+3 ----
    bf16x8 bfr[4], af[4];
#pragma unroll
    for (int ni = 0; ni < 4; ni++) bfr[ni] = LDB(slot, ni);
#pragma unroll
    for (int mi = 0; mi < 4; mi++) af[mi] = LDA(slot, mi);
    if (T + 3 < nt) STAGE(T + 3, 0, 2);
    __builtin_amdgcn_s_setprio(1);
#pragma unroll
    for (int mi = 0; mi < 4; mi++)
#pragma unroll
      for (int ni = 0; ni < 4; ni++)
        acc[mi][ni] = __builtin_amdgcn_mfma_f32_16x16x32_bf16(af[mi], bfr[ni], acc[mi][ni], 0, 0, 0);
    __builtin_amdgcn_s_setprio(0);
    __builtin_amdgcn_s_barrier();
    // ---- phase 1: A frags mi 4..7, stage second half of tile T+3 ----
#pragma unroll
    for (int mi = 0; mi < 4; mi++) af[mi] = LDA(slot, 4 + mi);
    if (T + 3 < nt) STAGE(T + 3, 2, 4);
    __builtin_amdgcn_s_setprio(1);
#pragma unroll
    for (int mi = 0; mi < 4; mi++)
#pragma unroll
      for (int ni = 0; ni < 4; ni++)
        acc[4 + mi][ni] = __builtin_amdgcn_mfma_f32_16x16x32_bf16(af[mi], bfr[ni], acc[4 + mi][ni], 0, 0, 0);
    __builtin_amdgcn_s_setprio(0);
    // ---- tile boundary: counted wait (tile T+1 resident, newer tiles in flight) ----
    int rem = nt - 1 - T;
    if (rem > 0) {
      if (rem >= 3)      asm volatile("s_waitcnt vmcnt(8)" ::: "memory");
      else if (rem == 2) asm volatile("s_waitcnt vmcnt(4)" ::: "memory");
      else               asm volatile("s_waitcnt vmcnt(0)" ::: "memory");
      __builtin_amdgcn_s_barrier();
      __builtin_amdgcn_sched_barrier(0);
    }
  }
  // ---- epilogue ----
#pragma unroll
  for (int mi = 0; mi < 8; mi++)
#pragma unroll
    for (int ni = 0; ni < 4; ni++)
#pragma unroll
      for (int j = 0; j < 4; j++) {
        size_t r = (size_t)bm * 256 + wr * 128 + mi * 16 + lg * 4 + j;
        size_t c = (size_t)bn * 256 + wc * 64 + ni * 16 + lr;
        C[r * Ndim + c] = (bf16)acc[mi][ni][j];
      }
}

// ---------------- bf16 GEMM (m97 structure), used for the output GEMM ----------------
template<int WRITE_BF16>
__global__ __launch_bounds__(256) void gemm_bt_k(const bf16* __restrict__ A, const bf16* __restrict__ Bt,
                                                 void* __restrict__ Cp, int Ndim, int K) {
  __shared__ bf16 As[128][64];
  __shared__ bf16 Bs[128][64];
  int bn = blockIdx.x, bm = blockIdx.y;
  int t = threadIdx.x, lane = t & 63, wid = t >> 6;
  int lr = lane & 15, lg = lane >> 4;
  int wm = (wid >> 1) * 64, wn = (wid & 1) * 64;
  f32x4 acc[4][4] = {};
  const bf16* Ab = A + (size_t)bm * 128 * K;
  const bf16* Bb = Bt + (size_t)bn * 128 * K;
  for (int k0 = 0; k0 < K; k0 += 64) {
    __syncthreads();
#pragma unroll
    for (int i = 0; i < 4; i++) {
      int ch = i * 256 + t;
      int row = ch >> 3, c8 = (ch & 7) * 8;
      gload_lds16(Ab + (size_t)row * K + k0 + c8, &As[0][0] + ch * 8);
      gload_lds16(Bb + (size_t)row * K + k0 + c8, &Bs[0][0] + ch * 8);
    }
    __syncthreads();
#pragma unroll
    for (int ks = 0; ks < 2; ks++) {
      bf16x8 af[4], bfr[4];
#pragma unroll
      for (int i = 0; i < 4; i++) af[i]  = *reinterpret_cast<const bf16x8*>(&As[wm + i * 16 + lr][ks * 32 + lg * 8]);
#pragma unroll
      for (int i = 0; i < 4; i++) bfr[i] = *reinterpret_cast<const bf16x8*>(&Bs[wn + i * 16 + lr][ks * 32 + lg * 8]);
#pragma unroll
      for (int mi = 0; mi < 4; mi++)
#pragma unroll
        for (int ni = 0; ni < 4; ni++)
          acc[mi][ni] = __builtin_amdgcn_mfma_f32_16x16x32_bf16(af[mi], bfr[ni], acc[mi][ni], 0, 0, 0);
    }
  }
#pragma unroll
  for (int mi = 0; mi < 4; mi++)
#pragma unroll
    for (int ni = 0; ni < 4; ni++)
#pragma unroll
      for (int j = 0; j < 4; j++) {
        size_t r = (size_t)bm * 128 + wm + mi * 16 + lg * 4 + j;
        size_t c = (size_t)bn * 128 + wn + ni * 16 + lr;
        if (WRITE_BF16) reinterpret_cast<bf16*>(Cp)[r * Ndim + c] = (bf16)acc[mi][ni][j];
        else            reinterpret_cast<float*>(Cp)[r * Ndim + c] = acc[mi][ni][j];
      }
}

// ---------------- fragment pre-pack: qkv -> qfrag/kfrag/vfrag (rope fused) ----------------
__global__ __launch_bounds__(256) void frag_all_k(const bf16* __restrict__ qkv, const float2* __restrict__ cs,
                                                  bf16* __restrict__ qf, bf16* __restrict__ kf,
                                                  bf16* __restrict__ vf) {
  __shared__ bf16 tl[3][64][72];
  int jt = blockIdx.x, bh = blockIdx.y;
  int b = bh >> 4, h = bh & 15;
  int t = threadIdx.x;
#pragma unroll
  for (int rep = 0; rep < 6; rep++) {
    int u = rep * 256 + t;
    int sel = u >> 9, w = u & 511;
    int kv = w >> 3, dc = w & 7;
    bf16x8 v = *reinterpret_cast<const bf16x8*>(
        qkv + ((size_t)(b * SEQ + jt * 64 + kv)) * QKVN + sel * DIMM + h * 64 + dc * 8);
    *reinterpret_cast<bf16x8*>(&tl[sel][kv][dc * 8]) = v;
  }
  __syncthreads();
  int lane2 = t & 63;
  int lo = lane2 & 31, hi = lane2 >> 5;
#pragma unroll
  for (int rep = 0; rep < 2; rep++) {
    int sub = rep * 4 + (t >> 6);      // 0..7
    int g4 = sub >> 2, ks = sub & 3;
    int n_l = g4 * 32 + lo;
    int db = ks * 16 + hi * 8;
    int n = jt * 64 + n_l;
    float sg = (db < 32) ? -1.f : 1.f;
    {
      bf16x8 xv = *reinterpret_cast<const bf16x8*>(&tl[0][n_l][db]);
      bf16x8 yv = *reinterpret_cast<const bf16x8*>(&tl[0][n_l][db ^ 32]);
      bf16x8 ov;
#pragma unroll
      for (int e = 0; e < 8; e++) {
        float2 cz = cs[n * 64 + db + e];
        ov[e] = (bf16)(((float)xv[e] * cz.x + sg * (float)yv[e] * cz.y) * SCALEQ);
      }
      *reinterpret_cast<bf16x8*>(qf + ((size_t)((bh * 64 + jt * 2 + g4) * 4 + ks)) * 512 + lane2 * 8) = ov;
    }
    {
      bf16x8 xv = *reinterpret_cast<const bf16x8*>(&tl[1][n_l][db]);
      bf16x8 yv = *reinterpret_cast<const bf16x8*>(&tl[1][n_l][db ^ 32]);
      bf16x8 ov;
#pragma unroll
      for (int e = 0; e < 8; e++) {
        float2 cz = cs[n * 64 + db + e];
        ov[e] = (bf16)((float)xv[e] * cz.x + sg * (float)yv[e] * cz.y);
      }
      *reinterpret_cast<bf16x8*>(kf + ((size_t)((bh * 32 + jt) * 8 + g4 * 4 + ks)) * 512 + lane2 * 8) = ov;
    }
    {
      int d = g4 * 32 + lo, kvb = ks * 16 + hi * 8;
      bf16x8 ov;
#pragma unroll
      for (int e = 0; e < 8; e++) ov[e] = tl[2][kvb + e][d];
      *reinterpret_cast<bf16x8*>(vf + ((size_t)((bh * 32 + jt) * 8 + g4 * 4 + ks)) * 512 + lane2 * 8) = ov;
    }
  }
}

// ---------------- flash causal attention, swapped-QK 32x32, KV-split-4 + bf16 LDS merge ----------------
// grid (64, 32): x = band-rank (0 = heaviest), y = bh. 4 waves; wave w does tiles w, w+4, ...
__global__ __launch_bounds__(256, 8) void attn_k(const bf16* __restrict__ qf_g, const bf16* __restrict__ kf_g,
                                                 const bf16* __restrict__ vf_g, bf16* __restrict__ o) {
  __shared__ bf16 ldsO[4][2048];     // bf16 partials: 16 KB (was 32 KB fp32) -> 8 blocks/CU
  __shared__ float ldsM[4][32];
  __shared__ float ldsL[4][32];
  int band = 63 - blockIdx.x;          // heavy bands dispatched first (LPT)
  int bh = blockIdx.y;
  int b = bh >> 4, h = bh & 15;
  int T = (band >> 1) + 1;             // causal KV-tile count for this band
  int t = threadIdx.x, lane = t & 63, w = t >> 6;
  int lo = lane & 31, hi = lane >> 5;
  int qrow0 = band * 32;
  int qg = qrow0 + lo;
  const bf16* qp = qf_g + ((size_t)(bh * 64 + band) * 4) * 512 + lane * 8;
  bf16x8 qfr[4];
#pragma unroll
  for (int ks = 0; ks < 4; ks++) qfr[ks] = *reinterpret_cast<const bf16x8*>(qp + ks * 512);
  f32x16 accO0 = {}, accO1 = {};
  float m_run = -1e30f, l_run = 0.f;
  const bf16* kb = kf_g + (size_t)bh * 32 * 8 * 512 + lane * 8;
  const bf16* vb = vf_g + (size_t)bh * 32 * 8 * 512 + lane * 8;
  for (int jt = w; jt < T; jt += 4) {
    const bf16* kt = kb + (size_t)jt * 8 * 512;
    const bf16* vt = vb + (size_t)jt * 8 * 512;
    bf16x8 ka[8];
#pragma unroll
    for (int u = 0; u < 8; u++) ka[u] = *reinterpret_cast<const bf16x8*>(kt + u * 512);
    f32x16 s0 = {}, s1 = {};
#pragma unroll
    for (int ks = 0; ks < 4; ks++) s0 = mfma32(ka[ks], qfr[ks], s0);
#pragma unroll
    for (int ks = 0; ks < 4; ks++) s1 = mfma32(ka[4 + ks], qfr[ks], s1);
    if (jt == T - 1) {
      int kv0 = jt * 64 + 4 * hi;
#pragma unroll
      for (int r = 0; r < 16; r++) {
        int kvg = kv0 + (r & 3) + 8 * (r >> 2);
        if (kvg > qg) s0[r] = -1e30f;
        if (kvg + 32 > qg) s1[r] = -1e30f;
      }
    }
    float pmax = s0[0];
#pragma unroll
    for (int r = 1; r < 16; r++) pmax = fmaxf(pmax, s0[r]);
#pragma unroll
    for (int r = 0; r < 16; r++) pmax = fmaxf(pmax, s1[r]);
    pmax = fmaxf(pmax, __shfl_xor(pmax, 32, 64));
    if (__any(pmax > m_run + 8.f)) {
      float mn = fmaxf(m_run, pmax);
      float corr = __expf(m_run - mn);
      m_run = mn;
      l_run *= corr;
      if (hi == 0) ldsM[w][lo] = corr;
#pragma unroll
      for (int r = 0; r < 16; r++) {
        float c = ldsM[w][(r & 3) + 8 * (r >> 2) + 4 * hi];
        accO0[r] *= c;
        accO1[r] *= c;
      }
    }
    float rs = 0.f;
#pragma unroll
    for (int r = 0; r < 16; r++) { s0[r] = __expf(s0[r] - m_run); rs += s0[r]; }
#pragma unroll
    for (int r = 0; r < 16; r++) { s1[r] = __expf(s1[r] - m_run); rs += s1[r]; }
    rs += __shfl_xor(rs, 32, 64);
    l_run += rs;
#pragma unroll
    for (int ks = 0; ks < 4; ks++) {
      unsigned a0, a1, b0, b1;
      if (ks == 0) { a0 = cvtpk(s0[0], s0[1]);  a1 = cvtpk(s0[2], s0[3]);
                     b0 = cvtpk(s0[4], s0[5]);  b1 = cvtpk(s0[6], s0[7]); }
      else if (ks == 1) { a0 = cvtpk(s0[8], s0[9]);   a1 = cvtpk(s0[10], s0[11]);
                          b0 = cvtpk(s0[12], s0[13]); b1 = cvtpk(s0[14], s0[15]); }
      else if (ks == 2) { a0 = cvtpk(s1[0], s1[1]);  a1 = cvtpk(s1[2], s1[3]);
                          b0 = cvtpk(s1[4], s1[5]);  b1 = cvtpk(s1[6], s1[7]); }
      else { a0 = cvtpk(s1[8], s1[9]);   a1 = cvtpk(s1[10], s1[11]);
             b0 = cvtpk(s1[12], s1[13]); b1 = cvtpk(s1[14], s1[15]); }
      int2v r0 = __builtin_amdgcn_permlane32_swap((int)a0, (int)b0, false, false);
      int2v r1 = __builtin_amdgcn_permlane32_swap((int)a1, (int)b1, false, false);
      int4v wv; wv[0] = r0[0]; wv[1] = r1[0]; wv[2] = r0[1]; wv[3] = r1[1];
      bf16x8 pa = __builtin_bit_cast(bf16x8, wv);
      bf16x8 v0 = *reinterpret_cast<const bf16x8*>(vt + (0 + ks) * 512);
      bf16x8 v1 = *reinterpret_cast<const bf16x8*>(vt + (4 + ks) * 512);
      accO0 = mfma32(pa, v0, accO0);
      accO1 = mfma32(pa, v1, accO1);
    }
  }
  if (hi == 0) { ldsM[w][lo] = m_run; ldsL[w][lo] = l_run; }
#pragma unroll
  for (int r = 0; r < 16; r++) {
    int q = (r & 3) + 8 * (r >> 2) + 4 * hi;
    ldsO[w][q * 64 + lo] = (bf16)accO0[r];
    ldsO[w][q * 64 + 32 + lo] = (bf16)accO1[r];
  }
  __syncthreads();
  {
    int q = t >> 3, d0 = (t & 7) * 8;
    float m0 = ldsM[0][q], m1 = ldsM[1][q], m2 = ldsM[2][q], m3 = ldsM[3][q];
    float mstar = fmaxf(fmaxf(m0, m1), fmaxf(m2, m3));
    float lsum = 0.f;
    float oacc[8] = {};
#pragma unroll
    for (int w2 = 0; w2 < 4; w2++) {
      float sc = __expf(ldsM[w2][q] - mstar);
      lsum += sc * ldsL[w2][q];
      bf16x8 pv = *reinterpret_cast<const bf16x8*>(&ldsO[w2][q * 64 + d0]);
#pragma unroll
      for (int e = 0; e < 8; e++) oacc[e] += sc * (float)pv[e];
    }
    float inv = 1.0f / lsum;
    bf16x8 ov;
#pragma unroll
    for (int e = 0; e < 8; e++) ov[e] = (bf16)(oacc[e] * inv);
    *reinterpret_cast<bf16x8*>(o + ((size_t)(b * SEQ + qrow0 + q)) * DIMM + h * 64 + d0) = ov;
  }
}

extern "C" void kernel_launch(void* const* d_in, const int* in_sizes, int n_in,
                              void* d_out, int out_size, void* d_ws, size_t ws_size,
                              hipStream_t stream) {
  const float* x    = (const float*)d_in[0];
  const float* rpe  = (const float*)d_in[1];
  const float* lnw  = (const float*)d_in[2];
  const float* lnb  = (const float*)d_in[3];
  const float* wqkv = (const float*)d_in[4];
  const float* wout = (const float*)d_in[5];

  char* ws = (char*)d_ws;
  bf16*   xn    = (bf16*)(ws);                 //  8 MB: 4096x1024
  bf16*   wqkvT = (bf16*)(ws + 8388608);       //  6 MB: 3072x1024
  bf16*   woutT = (bf16*)(ws + 14680064);      //  2 MB: 1024x1024
  bf16*   qkv   = (bf16*)(ws + 16777216);      // 24 MB: 4096x3072
  bf16*   qfrag = (bf16*)(ws + 41943040);      //  8 MB
  bf16*   kfrag = (bf16*)(ws + 50331648);      //  8 MB
  bf16*   vfrag = (bf16*)(ws + 58720256);      //  8 MB
  bf16*   obuf  = (bf16*)(ws + 67108864);      //  8 MB: 4096x1024
  float2* cs    = (float2*)(ws + 75497472);    //  1 MB: 2048x64

  transpose_cast_k<<<dim3(96, 32), 256, 0, stream>>>(wqkv, wqkvT, 1024, 3072);
  transpose_cast_k<<<dim3(32, 32), 256, 0, stream>>>(wout, woutT, 1024, 1024);
  rope_table_k<<<512, 256, 0, stream>>>(rpe, cs);
  ln_k<<<4096, 256, 0, stream>>>(x, lnw, lnb, xn);
  gemm256_k<<<dim3(12, 16), 512, 0, stream>>>(xn, wqkvT, qkv, 3072, 1024);
  frag_all_k<<<dim3(32, 32), 256, 0, stream>>>(qkv, cs, qfrag, kfrag, vfrag);
  attn_k<<<dim3(64, 32), 256, 0, stream>>>(qfrag, kfrag, vfrag, obuf);
  gemm_bt_k<0><<<dim3(8, 32), 256, 0, stream>>>(obuf, woutT, (float*)d_out, 1024, 1024);
}

// Round 8
// 222.418 us; speedup vs baseline: 2.4220x; 2.4220x over previous
//
#include <hip/hip_runtime.h>
#include <hip/hip_bf16.h>

typedef __bf16 bf16;
typedef __attribute__((ext_vector_type(8))) __bf16 bf16x8;
typedef __attribute__((ext_vector_type(4))) __bf16 bf16x4;
typedef __attribute__((ext_vector_type(4))) float f32x4;
typedef __attribute__((ext_vector_type(16))) float f32x16;
typedef __attribute__((ext_vector_type(2))) int int2v;
typedef __attribute__((ext_vector_type(4))) int int4v;

#define HEADS 16
#define DHEAD 64
#define SEQ 2048
#define DIMM 1024
#define QKVN (3*DIMM)
#define SCALEQ 0.125f

__device__ __forceinline__ void gload_lds16(const bf16* g, bf16* l) {
  __builtin_amdgcn_global_load_lds(
      (const __attribute__((address_space(1))) void*)g,
      (__attribute__((address_space(3))) void*)l, 16, 0, 0);
}

__device__ __forceinline__ f32x16 mfma32(bf16x8 a, bf16x8 b, f32x16 c) {
  return __builtin_amdgcn_mfma_f32_32x32x16_bf16(a, b, c, 0, 0, 0);
}

__device__ __forceinline__ unsigned cvtpk(float a, float b) {
  unsigned r;
  asm("v_cvt_pk_bf16_f32 %0, %1, %2" : "=v"(r) : "v"(a), "v"(b));
  return r;
}

// ---------------- transpose + cast fp32 -> bf16 (out = in^T) ----------------
__global__ __launch_bounds__(256) void transpose_cast_k(const float* __restrict__ in,
                                                        bf16* __restrict__ out, int R, int C) {
  __shared__ bf16 tile[32][33];
  int bc = blockIdx.x, br = blockIdx.y;
  int t = threadIdx.x;
  int c = t & 31, r0 = t >> 5;
  for (int i = 0; i < 4; i++) {
    int r = r0 + i * 8;
    tile[r][c] = (bf16)in[(size_t)(br * 32 + r) * C + bc * 32 + c];
  }
  __syncthreads();
  for (int i = 0; i < 4; i++) {
    int r = r0 + i * 8;
    out[(size_t)(bc * 32 + r) * R + br * 32 + c] = tile[c][r];
  }
}

// ---------------- rope cos/sin table ----------------
__global__ void rope_table_k(const float* __restrict__ pos, float2* __restrict__ cs) {
  int i = blockIdx.x * 256 + threadIdx.x;  // 2048*64 = 131072
  float p = pos[i];
  cs[i] = make_float2(cosf(p), sinf(p));
}

// ---------------- layernorm fp32 -> bf16 ----------------
__global__ __launch_bounds__(256) void ln_k(const float* __restrict__ x, const float* __restrict__ w,
                                            const float* __restrict__ bsh, bf16* __restrict__ xn) {
  int row = blockIdx.x, t = threadIdx.x;
  const float4 v = reinterpret_cast<const float4*>(x + (size_t)row * DIMM)[t];
  float s1 = v.x + v.y + v.z + v.w;
  float s2 = v.x * v.x + v.y * v.y + v.z * v.z + v.w * v.w;
  for (int off = 1; off < 64; off <<= 1) {
    s1 += __shfl_xor(s1, off, 64);
    s2 += __shfl_xor(s2, off, 64);
  }
  __shared__ float red[8];
  int wv = t >> 6;
  if ((t & 63) == 0) { red[wv * 2] = s1; red[wv * 2 + 1] = s2; }
  __syncthreads();
  s1 = red[0] + red[2] + red[4] + red[6];
  s2 = red[1] + red[3] + red[5] + red[7];
  float mu = s1 * (1.0f / DIMM);
  float var = s2 * (1.0f / DIMM) - mu * mu;
  float rs = rsqrtf(var + 1e-5f);
  const float4 wv4 = reinterpret_cast<const float4*>(w)[t];
  const float4 bv4 = reinterpret_cast<const float4*>(bsh)[t];
  bf16x4 o;
  o[0] = (bf16)((v.x - mu) * rs * wv4.x + bv4.x);
  o[1] = (bf16)((v.y - mu) * rs * wv4.y + bv4.y);
  o[2] = (bf16)((v.z - mu) * rs * wv4.z + bv4.z);
  o[3] = (bf16)((v.w - mu) * rs * wv4.w + bv4.w);
  *reinterpret_cast<bf16x4*>(xn + (size_t)row * DIMM + t * 4) = o;
}

// ---------------- 256x256 pipelined bf16 GEMM: C[M,N] = A[M,K] * Bt[N,K]^T ----------------
// 512 threads (8 waves, 2Mx4N), BK=32, 4-slot LDS ring (128 KB), staging 3 K-tiles ahead
// with counted vmcnt; st_16x32 XOR swizzle (linear dest + inv-swz source + swz read).
__global__ __launch_bounds__(512, 2) void gemm256_k(const bf16* __restrict__ A, const bf16* __restrict__ Bt,
                                                    bf16* __restrict__ C, int Ndim, int K) {
  __shared__ bf16 lds[4][2][8192];   // [slot][A/B][256 rows x 32 cols]
  const int t = threadIdx.x, lane = t & 63, w = t >> 6;
  const int wr = w >> 2, wc = w & 3;
  const int lr = lane & 15, lg = lane >> 4;
  const int bn = blockIdx.x, bm = blockIdx.y;
  const bf16* Ab = A + (size_t)(bm * 256) * K;
  const bf16* Bb = Bt + (size_t)(bn * 256) * K;
  const int nt = K >> 5;   // K-tiles of 32 (requires nt >= 4)

  // stage chunks [i0,i1) of tile T into slot T&3 (4 chunks of 16B per thread per tile)
  auto STAGE = [&](int T, int i0, int i1) {
    int k0 = T << 5;
    for (int i = i0; i < i1; ++i) {
      int c = t + i * 512;               // 0..2047 chunks of 16B (A: 0..1023, B: 1024..2047)
      int Lt = c * 16;
      int isB = Lt >> 14;
      int Lh = Lt & 16383;               // byte within the 16 KB region
      int Ls = Lh ^ (((Lh >> 9) & 1) << 5);   // inverse-swizzled source byte
      int elem = Ls >> 1;
      int row = elem >> 5, col = elem & 31;
      const bf16* src = (isB ? Bb : Ab) + (size_t)row * K + k0 + col;
      gload_lds16(src, &lds[T & 3][isB][0] + (Lh >> 1));
    }
  };
  auto LDA = [&](int slot, int mi) -> bf16x8 {
    int row = wr * 128 + mi * 16 + lr;
    int L0 = row * 64 + lg * 16;
    int L = L0 ^ (((L0 >> 9) & 1) << 5);
    return *reinterpret_cast<const bf16x8*>(reinterpret_cast<const char*>(&lds[slot][0][0]) + L);
  };
  auto LDB = [&](int slot, int ni) -> bf16x8 {
    int row = wc * 64 + ni * 16 + lr;
    int L0 = row * 64 + lg * 16;
    int L = L0 ^ (((L0 >> 9) & 1) << 5);
    return *reinterpret_cast<const bf16x8*>(reinterpret_cast<const char*>(&lds[slot][1][0]) + L);
  };

  f32x4 acc[8][4] = {};
  STAGE(0, 0, 4); STAGE(1, 0, 4); STAGE(2, 0, 4);
  asm volatile("s_waitcnt vmcnt(8)" ::: "memory");   // tile 0 resident; tiles 1,2 in flight
  __builtin_amdgcn_s_barrier();
  __builtin_amdgcn_sched_barrier(0);

  for (int T = 0; T < nt; ++T) {
    int slot = T & 3;
    // ---- phase 0: B frags + A frags mi 0..3, stage first half of tile T+3 ----
    bf16x8 bfr[4], af[4];
#pragma unroll
    for (int ni = 0; ni < 4; ni++) bfr[ni] = LDB(slot, ni);
#pragma unroll
    for (int mi = 0; mi < 4; mi++) af[mi] = LDA(slot, mi);
    if (T + 3 < nt) STAGE(T + 3, 0, 2);
    __builtin_amdgcn_s_setprio(1);
#pragma unroll
    for (int mi = 0; mi < 4; mi++)
#pragma unroll
      for (int ni = 0; ni < 4; ni++)
        acc[mi][ni] = __builtin_amdgcn_mfma_f32_16x16x32_bf16(af[mi], bfr[ni], acc[mi][ni], 0, 0, 0);
    __builtin_amdgcn_s_setprio(0);
    __builtin_amdgcn_s_barrier();
    // ---- phase 1: A frags mi 4..7, stage second half of tile T+3 ----
#pragma unroll
    for (int mi = 0; mi < 4; mi++) af[mi] = LDA(slot, 4 + mi);
    if (T + 3 < nt) STAGE(T + 3, 2, 4);
    __builtin_amdgcn_s_setprio(1);
#pragma unroll
    for (int mi = 0; mi < 4; mi++)
#pragma unroll
      for (int ni = 0; ni < 4; ni++)
        acc[4 + mi][ni] = __builtin_amdgcn_mfma_f32_16x16x32_bf16(af[mi], bfr[ni], acc[4 + mi][ni], 0, 0, 0);
    __builtin_amdgcn_s_setprio(0);
    // ---- tile boundary: counted wait (tile T+1 resident, newer tiles in flight) ----
    int rem = nt - 1 - T;
    if (rem > 0) {
      if (rem >= 3)      asm volatile("s_waitcnt vmcnt(8)" ::: "memory");
      else if (rem == 2) asm volatile("s_waitcnt vmcnt(4)" ::: "memory");
      else               asm volatile("s_waitcnt vmcnt(0)" ::: "memory");
      __builtin_amdgcn_s_barrier();
      __builtin_amdgcn_sched_barrier(0);
    }
  }
  // ---- epilogue ----
#pragma unroll
  for (int mi = 0; mi < 8; mi++)
#pragma unroll
    for (int ni = 0; ni < 4; ni++)
#pragma unroll
      for (int j = 0; j < 4; j++) {
        size_t r = (size_t)bm * 256 + wr * 128 + mi * 16 + lg * 4 + j;
        size_t c = (size_t)bn * 256 + wc * 64 + ni * 16 + lr;
        C[r * Ndim + c] = (bf16)acc[mi][ni][j];
      }
}

// ---------------- bf16 GEMM (m97 structure), used for the output GEMM ----------------
template<int WRITE_BF16>
__global__ __launch_bounds__(256) void gemm_bt_k(const bf16* __restrict__ A, const bf16* __restrict__ Bt,
                                                 void* __restrict__ Cp, int Ndim, int K) {
  __shared__ bf16 As[128][64];
  __shared__ bf16 Bs[128][64];
  int bn = blockIdx.x, bm = blockIdx.y;
  int t = threadIdx.x, lane = t & 63, wid = t >> 6;
  int lr = lane & 15, lg = lane >> 4;
  int wm = (wid >> 1) * 64, wn = (wid & 1) * 64;
  f32x4 acc[4][4] = {};
  const bf16* Ab = A + (size_t)bm * 128 * K;
  const bf16* Bb = Bt + (size_t)bn * 128 * K;
  for (int k0 = 0; k0 < K; k0 += 64) {
    __syncthreads();
#pragma unroll
    for (int i = 0; i < 4; i++) {
      int ch = i * 256 + t;
      int row = ch >> 3, c8 = (ch & 7) * 8;
      gload_lds16(Ab + (size_t)row * K + k0 + c8, &As[0][0] + ch * 8);
      gload_lds16(Bb + (size_t)row * K + k0 + c8, &Bs[0][0] + ch * 8);
    }
    __syncthreads();
#pragma unroll
    for (int ks = 0; ks < 2; ks++) {
      bf16x8 af[4], bfr[4];
#pragma unroll
      for (int i = 0; i < 4; i++) af[i]  = *reinterpret_cast<const bf16x8*>(&As[wm + i * 16 + lr][ks * 32 + lg * 8]);
#pragma unroll
      for (int i = 0; i < 4; i++) bfr[i] = *reinterpret_cast<const bf16x8*>(&Bs[wn + i * 16 + lr][ks * 32 + lg * 8]);
#pragma unroll
      for (int mi = 0; mi < 4; mi++)
#pragma unroll
        for (int ni = 0; ni < 4; ni++)
          acc[mi][ni] = __builtin_amdgcn_mfma_f32_16x16x32_bf16(af[mi], bfr[ni], acc[mi][ni], 0, 0, 0);
    }
  }
#pragma unroll
  for (int mi = 0; mi < 4; mi++)
#pragma unroll
    for (int ni = 0; ni < 4; ni++)
#pragma unroll
      for (int j = 0; j < 4; j++) {
        size_t r = (size_t)bm * 128 + wm + mi * 16 + lg * 4 + j;
        size_t c = (size_t)bn * 128 + wn + ni * 16 + lr;
        if (WRITE_BF16) reinterpret_cast<bf16*>(Cp)[r * Ndim + c] = (bf16)acc[mi][ni][j];
        else            reinterpret_cast<float*>(Cp)[r * Ndim + c] = acc[mi][ni][j];
      }
}

// ---------------- fragment pre-pack: qkv -> qfrag/kfrag/vfrag (rope fused) ----------------
__global__ __launch_bounds__(256) void frag_all_k(const bf16* __restrict__ qkv, const float2* __restrict__ cs,
                                                  bf16* __restrict__ qf, bf16* __restrict__ kf,
                                                  bf16* __restrict__ vf) {
  __shared__ bf16 tl[3][64][72];
  int jt = blockIdx.x, bh = blockIdx.y;
  int b = bh >> 4, h = bh & 15;
  int t = threadIdx.x;
#pragma unroll
  for (int rep = 0; rep < 6; rep++) {
    int u = rep * 256 + t;
    int sel = u >> 9, w = u & 511;
    int kv = w >> 3, dc = w & 7;
    bf16x8 v = *reinterpret_cast<const bf16x8*>(
        qkv + ((size_t)(b * SEQ + jt * 64 + kv)) * QKVN + sel * DIMM + h * 64 + dc * 8);
    *reinterpret_cast<bf16x8*>(&tl[sel][kv][dc * 8]) = v;
  }
  __syncthreads();
  int lane2 = t & 63;
  int lo = lane2 & 31, hi = lane2 >> 5;
#pragma unroll
  for (int rep = 0; rep < 2; rep++) {
    int sub = rep * 4 + (t >> 6);      // 0..7
    int g4 = sub >> 2, ks = sub & 3;
    int n_l = g4 * 32 + lo;
    int db = ks * 16 + hi * 8;
    int n = jt * 64 + n_l;
    float sg = (db < 32) ? -1.f : 1.f;
    {
      bf16x8 xv = *reinterpret_cast<const bf16x8*>(&tl[0][n_l][db]);
      bf16x8 yv = *reinterpret_cast<const bf16x8*>(&tl[0][n_l][db ^ 32]);
      bf16x8 ov;
#pragma unroll
      for (int e = 0; e < 8; e++) {
        float2 cz = cs[n * 64 + db + e];
        ov[e] = (bf16)(((float)xv[e] * cz.x + sg * (float)yv[e] * cz.y) * SCALEQ);
      }
      *reinterpret_cast<bf16x8*>(qf + ((size_t)((bh * 64 + jt * 2 + g4) * 4 + ks)) * 512 + lane2 * 8) = ov;
    }
    {
      bf16x8 xv = *reinterpret_cast<const bf16x8*>(&tl[1][n_l][db]);
      bf16x8 yv = *reinterpret_cast<const bf16x8*>(&tl[1][n_l][db ^ 32]);
      bf16x8 ov;
#pragma unroll
      for (int e = 0; e < 8; e++) {
        float2 cz = cs[n * 64 + db + e];
        ov[e] = (bf16)((float)xv[e] * cz.x + sg * (float)yv[e] * cz.y);
      }
      *reinterpret_cast<bf16x8*>(kf + ((size_t)((bh * 32 + jt) * 8 + g4 * 4 + ks)) * 512 + lane2 * 8) = ov;
    }
    {
      int d = g4 * 32 + lo, kvb = ks * 16 + hi * 8;
      bf16x8 ov;
#pragma unroll
      for (int e = 0; e < 8; e++) ov[e] = tl[2][kvb + e][d];
      *reinterpret_cast<bf16x8*>(vf + ((size_t)((bh * 32 + jt) * 8 + g4 * 4 + ks)) * 512 + lane2 * 8) = ov;
    }
  }
}

// ---------------- flash causal attention, swapped-QK 32x32, KV-split-4 + bf16 LDS merge ----------------
// grid (64, 32): x = band-rank (0 = heaviest), y = bh. 4 waves; wave w does tiles w, w+4, ...
__global__ __launch_bounds__(256, 4) void attn_k(const bf16* __restrict__ qf_g, const bf16* __restrict__ kf_g,
                                                 const bf16* __restrict__ vf_g, bf16* __restrict__ o) {
  __shared__ bf16 ldsO[4][2048];     // bf16 partials: 16 KB -> ~8 blocks/CU (VGPR-limited)
  __shared__ float ldsM[4][32];
  __shared__ float ldsL[4][32];
  int band = 63 - blockIdx.x;          // heavy bands dispatched first (LPT)
  int bh = blockIdx.y;
  int b = bh >> 4, h = bh & 15;
  int T = (band >> 1) + 1;             // causal KV-tile count for this band
  int t = threadIdx.x, lane = t & 63, w = t >> 6;
  int lo = lane & 31, hi = lane >> 5;
  int qrow0 = band * 32;
  int qg = qrow0 + lo;
  const bf16* qp = qf_g + ((size_t)(bh * 64 + band) * 4) * 512 + lane * 8;
  bf16x8 qfr[4];
#pragma unroll
  for (int ks = 0; ks < 4; ks++) qfr[ks] = *reinterpret_cast<const bf16x8*>(qp + ks * 512);
  f32x16 accO0 = {}, accO1 = {};
  float m_run = -1e30f, l_run = 0.f;
  const bf16* kb = kf_g + (size_t)bh * 32 * 8 * 512 + lane * 8;
  const bf16* vb = vf_g + (size_t)bh * 32 * 8 * 512 + lane * 8;
  for (int jt = w; jt < T; jt += 4) {
    const bf16* kt = kb + (size_t)jt * 8 * 512;
    const bf16* vt = vb + (size_t)jt * 8 * 512;
    bf16x8 ka[8];
#pragma unroll
    for (int u = 0; u < 8; u++) ka[u] = *reinterpret_cast<const bf16x8*>(kt + u * 512);
    f32x16 s0 = {}, s1 = {};
#pragma unroll
    for (int ks = 0; ks < 4; ks++) s0 = mfma32(ka[ks], qfr[ks], s0);
#pragma unroll
    for (int ks = 0; ks < 4; ks++) s1 = mfma32(ka[4 + ks], qfr[ks], s1);
    if (jt == T - 1) {
      int kv0 = jt * 64 + 4 * hi;
#pragma unroll
      for (int r = 0; r < 16; r++) {
        int kvg = kv0 + (r & 3) + 8 * (r >> 2);
        if (kvg > qg) s0[r] = -1e30f;
        if (kvg + 32 > qg) s1[r] = -1e30f;
      }
    }
    float pmax = s0[0];
#pragma unroll
    for (int r = 1; r < 16; r++) pmax = fmaxf(pmax, s0[r]);
#pragma unroll
    for (int r = 0; r < 16; r++) pmax = fmaxf(pmax, s1[r]);
    pmax = fmaxf(pmax, __shfl_xor(pmax, 32, 64));
    if (__any(pmax > m_run + 8.f)) {
      float mn = fmaxf(m_run, pmax);
      float corr = __expf(m_run - mn);
      m_run = mn;
      l_run *= corr;
      if (hi == 0) ldsM[w][lo] = corr;
#pragma unroll
      for (int r = 0; r < 16; r++) {
        float c = ldsM[w][(r & 3) + 8 * (r >> 2) + 4 * hi];
        accO0[r] *= c;
        accO1[r] *= c;
      }
    }
    float rs = 0.f;
#pragma unroll
    for (int r = 0; r < 16; r++) { s0[r] = __expf(s0[r] - m_run); rs += s0[r]; }
#pragma unroll
    for (int r = 0; r < 16; r++) { s1[r] = __expf(s1[r] - m_run); rs += s1[r]; }
    rs += __shfl_xor(rs, 32, 64);
    l_run += rs;
#pragma unroll
    for (int ks = 0; ks < 4; ks++) {
      unsigned a0, a1, b0, b1;
      if (ks == 0) { a0 = cvtpk(s0[0], s0[1]);  a1 = cvtpk(s0[2], s0[3]);
                     b0 = cvtpk(s0[4], s0[5]);  b1 = cvtpk(s0[6], s0[7]); }
      else if (ks == 1) { a0 = cvtpk(s0[8], s0[9]);   a1 = cvtpk(s0[10], s0[11]);
                          b0 = cvtpk(s0[12], s0[13]); b1 = cvtpk(s0[14], s0[15]); }
      else if (ks == 2) { a0 = cvtpk(s1[0], s1[1]);  a1 = cvtpk(s1[2], s1[3]);
                          b0 = cvtpk(s1[4], s1[5]);  b1 = cvtpk(s1[6], s1[7]); }
      else { a0 = cvtpk(s1[8], s1[9]);   a1 = cvtpk(s1[10], s1[11]);
             b0 = cvtpk(s1[12], s1[13]); b1 = cvtpk(s1[14], s1[15]); }
      int2v r0 = __builtin_amdgcn_permlane32_swap((int)a0, (int)b0, false, false);
      int2v r1 = __builtin_amdgcn_permlane32_swap((int)a1, (int)b1, false, false);
      int4v wv; wv[0] = r0[0]; wv[1] = r1[0]; wv[2] = r0[1]; wv[3] = r1[1];
      bf16x8 pa = __builtin_bit_cast(bf16x8, wv);
      bf16x8 v0 = *reinterpret_cast<const bf16x8*>(vt + (0 + ks) * 512);
      bf16x8 v1 = *reinterpret_cast<const bf16x8*>(vt + (4 + ks) * 512);
      accO0 = mfma32(pa, v0, accO0);
      accO1 = mfma32(pa, v1, accO1);
    }
  }
  if (hi == 0) { ldsM[w][lo] = m_run; ldsL[w][lo] = l_run; }
#pragma unroll
  for (int r = 0; r < 16; r++) {
    int q = (r & 3) + 8 * (r >> 2) + 4 * hi;
    ldsO[w][q * 64 + lo] = (bf16)accO0[r];
    ldsO[w][q * 64 + 32 + lo] = (bf16)accO1[r];
  }
  __syncthreads();
  {
    int q = t >> 3, d0 = (t & 7) * 8;
    float m0 = ldsM[0][q], m1 = ldsM[1][q], m2 = ldsM[2][q], m3 = ldsM[3][q];
    float mstar = fmaxf(fmaxf(m0, m1), fmaxf(m2, m3));
    float lsum = 0.f;
    float oacc[8] = {};
#pragma unroll
    for (int w2 = 0; w2 < 4; w2++) {
      float sc = __expf(ldsM[w2][q] - mstar);
      lsum += sc * ldsL[w2][q];
      bf16x8 pv = *reinterpret_cast<const bf16x8*>(&ldsO[w2][q * 64 + d0]);
#pragma unroll
      for (int e = 0; e < 8; e++) oacc[e] += sc * (float)pv[e];
    }
    float inv = 1.0f / lsum;
    bf16x8 ov;
#pragma unroll
    for (int e = 0; e < 8; e++) ov[e] = (bf16)(oacc[e] * inv);
    *reinterpret_cast<bf16x8*>(o + ((size_t)(b * SEQ + qrow0 + q)) * DIMM + h * 64 + d0) = ov;
  }
}

extern "C" void kernel_launch(void* const* d_in, const int* in_sizes, int n_in,
                              void* d_out, int out_size, void* d_ws, size_t ws_size,
                              hipStream_t stream) {
  const float* x    = (const float*)d_in[0];
  const float* rpe  = (const float*)d_in[1];
  const float* lnw  = (const float*)d_in[2];
  const float* lnb  = (const float*)d_in[3];
  const float* wqkv = (const float*)d_in[4];
  const float* wout = (const float*)d_in[5];

  char* ws = (char*)d_ws;
  bf16*   xn    = (bf16*)(ws);                 //  8 MB: 4096x1024
  bf16*   wqkvT = (bf16*)(ws + 8388608);       //  6 MB: 3072x1024
  bf16*   woutT = (bf16*)(ws + 14680064);      //  2 MB: 1024x1024
  bf16*   qkv   = (bf16*)(ws + 16777216);      // 24 MB: 4096x3072
  bf16*   qfrag = (bf16*)(ws + 41943040);      //  8 MB
  bf16*   kfrag = (bf16*)(ws + 50331648);      //  8 MB
  bf16*   vfrag = (bf16*)(ws + 58720256);      //  8 MB
  bf16*   obuf  = (bf16*)(ws + 67108864);      //  8 MB: 4096x1024
  float2* cs    = (float2*)(ws + 75497472);    //  1 MB: 2048x64

  transpose_cast_k<<<dim3(96, 32), 256, 0, stream>>>(wqkv, wqkvT, 1024, 3072);
  transpose_cast_k<<<dim3(32, 32), 256, 0, stream>>>(wout, woutT, 1024, 1024);
  rope_table_k<<<512, 256, 0, stream>>>(rpe, cs);
  ln_k<<<4096, 256, 0, stream>>>(x, lnw, lnb, xn);
  gemm256_k<<<dim3(12, 16), 512, 0, stream>>>(xn, wqkvT, qkv, 3072, 1024);
  frag_all_k<<<dim3(32, 32), 256, 0, stream>>>(qkv, cs, qfrag, kfrag, vfrag);
  attn_k<<<dim3(64, 32), 256, 0, stream>>>(qfrag, kfrag, vfrag, obuf);
  gemm_bt_k<0><<<dim3(8, 32), 256, 0, stream>>>(obuf, woutT, (float*)d_out, 1024, 1024);
}